// Round 3
// baseline (418.150 us; speedup 1.0000x reference)
//
#include <hip/hip_runtime.h>
#include <hip/hip_cooperative_groups.h>
#include <math.h>

namespace cg = cooperative_groups;

#define BS  128
#define OBJ 512
#define RNN 1024
#define HID 512
#define NCU 256

// tanh via fast exp: tanh(x) = sign(x) * (1 - e^{-2|x|}) / (1 + e^{-2|x|})
__device__ __forceinline__ float fast_tanh(float x) {
    float ax = fabsf(x);
    float e  = __expf(-2.0f * ax);                       // in (0,1]
    float r  = (1.0f - e) * __builtin_amdgcn_rcpf(1.0f + e);
    return copysignf(r, x);
}

// Merge two wave-wide partial sums (butterfly tree step).
__device__ __forceinline__ float combine2(float x, float y, int w) {
    int lane = threadIdx.x & 63;
    float send  = (lane & w) ? x : y;
    float other = __shfl_xor(send, w, 64);
    float keep  = (lane & w) ? y : x;
    return keep + other;
}

__device__ __forceinline__ float dot4(float4 a, float4 b, float s) {
    s = fmaf(a.x, b.x, s);
    s = fmaf(a.y, b.y, s);
    s = fmaf(a.z, b.z, s);
    s = fmaf(a.w, b.w, s);
    return s;
}

// ---------------- Phase helpers (shared by fused + fallback) ----------------

// att_h tile: one wave computes a 2(b) x 8(j) tile of h @ W^T.
__device__ __forceinline__ void phaseA_tile(
    int tile, int lane, const float* __restrict__ h, const float* __restrict__ W,
    float* __restrict__ att_h)
{
    const int b0 = (tile >> 6) * 2;
    const int j0 = (tile & 63) * 8;

    const float4* h4 = (const float4*)h;   // row stride 256 float4
    const float4* W4 = (const float4*)W;   // row stride 256 float4

    float4 ha[2][4];
#pragma unroll
    for (int bi = 0; bi < 2; ++bi)
#pragma unroll
        for (int i = 0; i < 4; ++i)
            ha[bi][i] = h4[(b0 + bi) * 256 + i * 64 + lane];

    float acc[16];
#pragma unroll
    for (int jj = 0; jj < 8; ++jj) {
        const int wbase = (j0 + jj) * 256;
        float4 w0 = W4[wbase + 0 * 64 + lane];
        float4 w1 = W4[wbase + 1 * 64 + lane];
        float4 w2 = W4[wbase + 2 * 64 + lane];
        float4 w3 = W4[wbase + 3 * 64 + lane];
#pragma unroll
        for (int bi = 0; bi < 2; ++bi) {
            float s = 0.f;
            s = dot4(ha[bi][0], w0, s);
            s = dot4(ha[bi][1], w1, s);
            s = dot4(ha[bi][2], w2, s);
            s = dot4(ha[bi][3], w3, s);
            acc[jj * 2 + bi] = s;   // idx bit0 = bi, bits1-3 = jj
        }
    }

    float t8[8];
#pragma unroll
    for (int i = 0; i < 8; ++i) t8[i] = combine2(acc[2 * i], acc[2 * i + 1], 1);
    float t4v[4];
#pragma unroll
    for (int i = 0; i < 4; ++i) t4v[i] = combine2(t8[2 * i], t8[2 * i + 1], 2);
    float t2v[2];
#pragma unroll
    for (int i = 0; i < 2; ++i) t2v[i] = combine2(t4v[2 * i], t4v[2 * i + 1], 4);
    float t1 = combine2(t2v[0], t2v[1], 8);
    t1 += __shfl_xor(t1, 16, 64);
    t1 += __shfl_xor(t1, 32, 64);

    if (lane < 16) {
        int bi = lane & 1;
        int jj = lane >> 1;
        att_h[(b0 + bi) * HID + j0 + jj] = t1;
    }
}

// scores for one (b, 8-object group): returns per-lane value; lanes 0..7 hold
// the 8 scores (already reduced).
__device__ __forceinline__ float phaseB_scores(
    int b, int o0, int lane,
    const float* __restrict__ att_feats, const float* __restrict__ att_h,
    const float* __restrict__ b_h2att, const float* __restrict__ w_alpha)
{
    const float4* ah4 = (const float4*)(att_h + b * HID);
    const float4* bb4 = (const float4*)b_h2att;
    const float4* wa4 = (const float4*)w_alpha;

    float4 a0 = ah4[lane],      a1 = ah4[64 + lane];
    float4 c0 = bb4[lane],      c1 = bb4[64 + lane];
    float4 hs0, hs1;
    hs0.x = a0.x + c0.x; hs0.y = a0.y + c0.y; hs0.z = a0.z + c0.z; hs0.w = a0.w + c0.w;
    hs1.x = a1.x + c1.x; hs1.y = a1.y + c1.y; hs1.z = a1.z + c1.z; hs1.w = a1.w + c1.w;
    float4 wa0 = wa4[lane], wa1 = wa4[64 + lane];

    const float4* f4 = (const float4*)att_feats + (size_t)(b * OBJ + o0) * (HID / 4);

    float acc[8];
#pragma unroll
    for (int oo = 0; oo < 8; ++oo) {
        float4 x0 = f4[oo * 128 + lane];
        float4 x1 = f4[oo * 128 + 64 + lane];
        float s = 0.f;
        s = fmaf(wa0.x, fast_tanh(x0.x + hs0.x), s);
        s = fmaf(wa0.y, fast_tanh(x0.y + hs0.y), s);
        s = fmaf(wa0.z, fast_tanh(x0.z + hs0.z), s);
        s = fmaf(wa0.w, fast_tanh(x0.w + hs0.w), s);
        s = fmaf(wa1.x, fast_tanh(x1.x + hs1.x), s);
        s = fmaf(wa1.y, fast_tanh(x1.y + hs1.y), s);
        s = fmaf(wa1.z, fast_tanh(x1.z + hs1.z), s);
        s = fmaf(wa1.w, fast_tanh(x1.w + hs1.w), s);
        acc[oo] = s;
    }

    float t4v[4];
#pragma unroll
    for (int i = 0; i < 4; ++i) t4v[i] = combine2(acc[2 * i], acc[2 * i + 1], 1);
    float t2v[2];
#pragma unroll
    for (int i = 0; i < 2; ++i) t2v[i] = combine2(t4v[2 * i], t4v[2 * i + 1], 2);
    float t1 = combine2(t2v[0], t2v[1], 4);
    t1 += __shfl_xor(t1, 8, 64);
    t1 += __shfl_xor(t1, 16, 64);
    t1 += __shfl_xor(t1, 32, 64);
    return t1;
}

// ---------------- Fused cooperative kernel ----------------
// Any grid size works (wave-stride loops). No softmax max-shift needed:
// |score| <= sum|w_alpha| ~ 18 -> exp in [e-18, e18], safe in fp32.
// b_alpha is a constant shift -> cancels in softmax -> dropped.
__global__ __launch_bounds__(256, 2) void fused_attn(
    const float* __restrict__ h, const float* __restrict__ att_feats,
    const int* __restrict__ masks, const float* __restrict__ W,
    const float* __restrict__ b_h2att, const float* __restrict__ w_alpha,
    float* __restrict__ out, float* __restrict__ att_h,
    float* __restrict__ sums, int nBlocks)
{
    cg::grid_group grid = cg::this_grid();
    const int lane = threadIdx.x & 63;
    const int wv   = blockIdx.x * 4 + (threadIdx.x >> 6);
    const int nWaves = nBlocks * 4;

    // zero the per-batch softmax denominators (d_ws is poisoned 0xAA)
    if (blockIdx.x == 0 && threadIdx.x < BS) sums[threadIdx.x] = 0.0f;

    for (int tile = wv; tile < 4096; tile += nWaves)
        phaseA_tile(tile, lane, h, W, att_h);

    __threadfence();
    grid.sync();

    for (int u = wv; u < 8192; u += nWaves) {
        const int b  = u >> 6;
        const int o0 = (u & 63) * 8;
        float t1 = phaseB_scores(b, o0, lane, att_feats, att_h, b_h2att, w_alpha);

        float e = 0.0f;
        if (lane < 8) {
            float m = (float)masks[b * OBJ + o0 + lane];
            e = __expf(t1) * m;
            out[b * OBJ + o0 + lane] = e;
        }
        float es = e;                       // lanes >=8 contribute 0
        es += __shfl_xor(es, 1, 64);
        es += __shfl_xor(es, 2, 64);
        es += __shfl_xor(es, 4, 64);
        if (lane == 0) atomicAdd(&sums[b], es);
    }

    __threadfence();
    grid.sync();

    for (int tid = blockIdx.x * 256 + threadIdx.x; tid < BS * OBJ;
         tid += nBlocks * 256) {
        const int b = tid >> 9;
        out[tid] = out[tid] / sums[b];
    }
}

// ---------------- Fallback path (proven Round-1 kernels) ----------------

__global__ __launch_bounds__(256) void k1_h2att(
    const float* __restrict__ h, const float* __restrict__ W,
    float* __restrict__ att_h)
{
    const int lane = threadIdx.x & 63;
    const int wv   = blockIdx.x * 4 + (threadIdx.x >> 6);
    phaseA_tile(wv, lane, h, W, att_h);
}

__global__ __launch_bounds__(256) void k2_scores(
    const float* __restrict__ att_feats, const float* __restrict__ att_h,
    const float* __restrict__ b_h2att, const float* __restrict__ w_alpha,
    float* __restrict__ scores)
{
    const int lane = threadIdx.x & 63;
    const int wv   = blockIdx.x * 4 + (threadIdx.x >> 6);
    const int b    = wv >> 6;
    const int o0   = (wv & 63) * 8;
    float t1 = phaseB_scores(b, o0, lane, att_feats, att_h, b_h2att, w_alpha);
    if (lane < 8) scores[b * OBJ + o0 + lane] = t1;
}

__global__ __launch_bounds__(256) void k3_softmax(
    float* __restrict__ scores_out, const int* __restrict__ masks)
{
    __shared__ float red[4];
    const int b    = blockIdx.x;
    const int t    = threadIdx.x;
    const int lane = t & 63;
    const int wv   = t >> 6;

    float s0 = scores_out[b * OBJ + t];
    float s1 = scores_out[b * OBJ + t + 256];
    float m0 = (float)masks[b * OBJ + t];
    float m1 = (float)masks[b * OBJ + t + 256];

    float mx = fmaxf(s0, s1);
#pragma unroll
    for (int w = 1; w <= 32; w <<= 1) mx = fmaxf(mx, __shfl_xor(mx, w, 64));
    if (lane == 0) red[wv] = mx;
    __syncthreads();
    mx = fmaxf(fmaxf(red[0], red[1]), fmaxf(red[2], red[3]));
    __syncthreads();

    float e0 = __expf(s0 - mx) * m0;
    float e1 = __expf(s1 - mx) * m1;
    float sm = e0 + e1;
#pragma unroll
    for (int w = 1; w <= 32; w <<= 1) sm += __shfl_xor(sm, w, 64);
    if (lane == 0) red[wv] = sm;
    __syncthreads();
    sm = (red[0] + red[1]) + (red[2] + red[3]);

    float inv = 1.0f / sm;
    scores_out[b * OBJ + t]       = e0 * inv;
    scores_out[b * OBJ + t + 256] = e1 * inv;
}

extern "C" void kernel_launch(void* const* d_in, const int* in_sizes, int n_in,
                              void* d_out, int out_size, void* d_ws, size_t ws_size,
                              hipStream_t stream)
{
    const float* h         = (const float*)d_in[0];
    const float* att_feats = (const float*)d_in[1];
    const int*   att_masks = (const int*)d_in[2];
    const float* W_h2att   = (const float*)d_in[3];
    const float* b_h2att   = (const float*)d_in[4];
    const float* w_alpha   = (const float*)d_in[5];
    // d_in[6] = b_alpha: constant shift, cancels exactly in softmax -> unused.

    float* out   = (float*)d_out;
    float* att_h = (float*)d_ws;                 // BS*HID floats = 256 KB
    float* sums  = (float*)d_ws + BS * HID;      // BS floats

    // Deterministic, capture-safe occupancy-based grid sizing for the
    // cooperative launch (same result on every call).
    int maxBlocksPerCU = 0;
    hipError_t qe = hipOccupancyMaxActiveBlocksPerMultiprocessor(
        &maxBlocksPerCU, (const void*)fused_attn, 256, 0);
    int nb = (qe == hipSuccess) ? maxBlocksPerCU * NCU : 0;
    if (nb > 1024) nb = 1024;

    hipError_t le = hipErrorUnknown;
    if (nb >= 64) {
        void* args[] = { (void*)&h, (void*)&att_feats, (void*)&att_masks,
                         (void*)&W_h2att, (void*)&b_h2att, (void*)&w_alpha,
                         (void*)&out, (void*)&att_h, (void*)&sums, (void*)&nb };
        le = hipLaunchCooperativeKernel((const void*)fused_attn, dim3(nb),
                                        dim3(256), args, 0, stream);
    }

    if (le != hipSuccess) {
        // Fallback: proven 3-kernel path.
        k1_h2att  <<<dim3(1024), dim3(256), 0, stream>>>(h, W_h2att, att_h);
        k2_scores <<<dim3(2048), dim3(256), 0, stream>>>(att_feats, att_h,
                                                         b_h2att, w_alpha, out);
        k3_softmax<<<dim3(BS),   dim3(256), 0, stream>>>(out, att_masks);
    }
}

// Round 4
// 216.915 us; speedup vs baseline: 1.9277x; 1.9277x over previous
//
#include <hip/hip_runtime.h>
#include <math.h>

#define BS  128
#define OBJ 512
#define RNN 1024
#define HID 512

// Merge two wave-wide partial sums (butterfly tree step).
__device__ __forceinline__ float combine2(float x, float y, int w) {
    int lane = threadIdx.x & 63;
    float send  = (lane & w) ? x : y;
    float other = __shfl_xor(send, w, 64);
    float keep  = (lane & w) ? y : x;
    return keep + other;
}

__device__ __forceinline__ float dot4(float4 a, float4 b, float s) {
    s = fmaf(a.x, b.x, s);
    s = fmaf(a.y, b.y, s);
    s = fmaf(a.z, b.z, s);
    s = fmaf(a.w, b.w, s);
    return s;
}

// K1: att_h[b,j] = sum_k h[b,k] * W[j,k]   (bias folded into K2)
// One wave computes a 2(b) x 8(j) tile via full-wave dot products.
__global__ __launch_bounds__(256) void k1_h2att(
    const float* __restrict__ h, const float* __restrict__ W,
    float* __restrict__ att_h)
{
    const int lane = threadIdx.x & 63;
    const int wv   = blockIdx.x * 4 + (threadIdx.x >> 6);
    const int b0   = (wv >> 6) * 2;
    const int j0   = (wv & 63) * 8;

    const float4* h4 = (const float4*)h;   // row stride 256 float4
    const float4* W4 = (const float4*)W;   // row stride 256 float4

    float4 ha[2][4];
#pragma unroll
    for (int bi = 0; bi < 2; ++bi)
#pragma unroll
        for (int i = 0; i < 4; ++i)
            ha[bi][i] = h4[(b0 + bi) * 256 + i * 64 + lane];

    float acc[16];
#pragma unroll
    for (int jj = 0; jj < 8; ++jj) {
        const int wbase = (j0 + jj) * 256;
        float4 w0 = W4[wbase + 0 * 64 + lane];
        float4 w1 = W4[wbase + 1 * 64 + lane];
        float4 w2 = W4[wbase + 2 * 64 + lane];
        float4 w3 = W4[wbase + 3 * 64 + lane];
#pragma unroll
        for (int bi = 0; bi < 2; ++bi) {
            float s = 0.f;
            s = dot4(ha[bi][0], w0, s);
            s = dot4(ha[bi][1], w1, s);
            s = dot4(ha[bi][2], w2, s);
            s = dot4(ha[bi][3], w3, s);
            acc[jj * 2 + bi] = s;   // idx bit0 = bi, bits1-3 = jj
        }
    }

    float t8[8];
#pragma unroll
    for (int i = 0; i < 8; ++i) t8[i] = combine2(acc[2 * i], acc[2 * i + 1], 1);
    float t4v[4];
#pragma unroll
    for (int i = 0; i < 4; ++i) t4v[i] = combine2(t8[2 * i], t8[2 * i + 1], 2);
    float t2v[2];
#pragma unroll
    for (int i = 0; i < 2; ++i) t2v[i] = combine2(t4v[2 * i], t4v[2 * i + 1], 4);
    float t1 = combine2(t2v[0], t2v[1], 8);
    t1 += __shfl_xor(t1, 16, 64);
    t1 += __shfl_xor(t1, 32, 64);

    if (lane < 16) {
        int bi = lane & 1;
        int jj = lane >> 1;
        att_h[(b0 + bi) * HID + j0 + jj] = t1;
    }
}

// K2: scores[b,o] = sum_h w_alpha[h] * tanh(att_feats[b,o,h] + att_h[b,h] + b_h2att[h])
// tanh(x) = 1 - 2/(1 + e^{2x});  score = sum(w) - 2 * sum(w * rcp(exp2(C*x)+1)),
// C = 2*log2(e).  b_alpha dropped (constant shift cancels in softmax).
// One wave per (b, 8 objects).  ALL 16 streaming float4 loads are issued into
// registers before the transcendental chain so memory latency is covered by
// in-flight loads (launch_bounds(256,4): VGPR cap 128 -> ~16 waves/CU).
__global__ __launch_bounds__(256, 4) void k2_scores(
    const float* __restrict__ att_feats, const float* __restrict__ att_h,
    const float* __restrict__ b_h2att, const float* __restrict__ w_alpha,
    float* __restrict__ scores)
{
    const int lane = threadIdx.x & 63;
    const int wv   = blockIdx.x * 4 + (threadIdx.x >> 6);
    const int b    = wv >> 6;
    const int o0   = (wv & 63) * 8;

    const float4* f4 = (const float4*)att_feats + (size_t)(b * OBJ + o0) * 128;

    // ---- issue all streaming loads first (16 x dwordx4 in flight) ----
    float4 x[16];
#pragma unroll
    for (int oo = 0; oo < 8; ++oo) {
        x[2 * oo]     = f4[oo * 128 + lane];
        x[2 * oo + 1] = f4[oo * 128 + 64 + lane];
    }

    // ---- hoisted per-wave vectors (L2-resident, reused 8x) ----
    const float C = 2.8853900817779268f;   // 2*log2(e)
    const float4* ah4 = (const float4*)(att_h + b * HID);
    const float4* bb4 = (const float4*)b_h2att;
    const float4* wa4 = (const float4*)w_alpha;

    float4 a0 = ah4[lane],  a1 = ah4[64 + lane];
    float4 c0 = bb4[lane],  c1 = bb4[64 + lane];
    float4 wa0 = wa4[lane], wa1 = wa4[64 + lane];

    float4 hs0, hs1;   // (att_h + bias) * C, pre-scaled for exp2
    hs0.x = (a0.x + c0.x) * C; hs0.y = (a0.y + c0.y) * C;
    hs0.z = (a0.z + c0.z) * C; hs0.w = (a0.w + c0.w) * C;
    hs1.x = (a1.x + c1.x) * C; hs1.y = (a1.y + c1.y) * C;
    hs1.z = (a1.z + c1.z) * C; hs1.w = (a1.w + c1.w) * C;

    float wsum = wa0.x + wa0.y + wa0.z + wa0.w + wa1.x + wa1.y + wa1.z + wa1.w;

    // ---- per-element: acc += w * rcp(exp2(fma(f, C, hs)) + 1) ----
    float acc[8];
#pragma unroll
    for (int oo = 0; oo < 8; ++oo) {
        const float4 x0 = x[2 * oo];
        const float4 x1 = x[2 * oo + 1];
        float s = 0.f;
        s = fmaf(wa0.x, __builtin_amdgcn_rcpf(exp2f(fmaf(x0.x, C, hs0.x)) + 1.0f), s);
        s = fmaf(wa0.y, __builtin_amdgcn_rcpf(exp2f(fmaf(x0.y, C, hs0.y)) + 1.0f), s);
        s = fmaf(wa0.z, __builtin_amdgcn_rcpf(exp2f(fmaf(x0.z, C, hs0.z)) + 1.0f), s);
        s = fmaf(wa0.w, __builtin_amdgcn_rcpf(exp2f(fmaf(x0.w, C, hs0.w)) + 1.0f), s);
        s = fmaf(wa1.x, __builtin_amdgcn_rcpf(exp2f(fmaf(x1.x, C, hs1.x)) + 1.0f), s);
        s = fmaf(wa1.y, __builtin_amdgcn_rcpf(exp2f(fmaf(x1.y, C, hs1.y)) + 1.0f), s);
        s = fmaf(wa1.z, __builtin_amdgcn_rcpf(exp2f(fmaf(x1.z, C, hs1.z)) + 1.0f), s);
        s = fmaf(wa1.w, __builtin_amdgcn_rcpf(exp2f(fmaf(x1.w, C, hs1.w)) + 1.0f), s);
        acc[oo] = s;
    }

    // ---- reduce: 8 accumulators -> lanes 0..7 hold sum(w*r) per object ----
    float t4v[4];
#pragma unroll
    for (int i = 0; i < 4; ++i) t4v[i] = combine2(acc[2 * i], acc[2 * i + 1], 1);
    float t2v[2];
#pragma unroll
    for (int i = 0; i < 2; ++i) t2v[i] = combine2(t4v[2 * i], t4v[2 * i + 1], 2);
    float t1 = combine2(t2v[0], t2v[1], 4);
    t1 += __shfl_xor(t1, 8, 64);
    t1 += __shfl_xor(t1, 16, 64);
    t1 += __shfl_xor(t1, 32, 64);

    // total sum of w_alpha across all 512 h (same for every object)
    float tw = wsum;
#pragma unroll
    for (int w = 1; w <= 32; w <<= 1) tw += __shfl_xor(tw, w, 64);

    if (lane < 8) scores[b * OBJ + o0 + lane] = tw - 2.0f * t1;
}

// K3: weight = e*m / sum(e*m), e = exp(s - max(s)).  In-place in d_out.
__global__ __launch_bounds__(256) void k3_softmax(
    float* __restrict__ scores_out, const int* __restrict__ masks)
{
    __shared__ float red[4];
    const int b    = blockIdx.x;
    const int t    = threadIdx.x;
    const int lane = t & 63;
    const int wv   = t >> 6;

    float s0 = scores_out[b * OBJ + t];
    float s1 = scores_out[b * OBJ + t + 256];
    float m0 = (float)masks[b * OBJ + t];
    float m1 = (float)masks[b * OBJ + t + 256];

    float mx = fmaxf(s0, s1);
#pragma unroll
    for (int w = 1; w <= 32; w <<= 1) mx = fmaxf(mx, __shfl_xor(mx, w, 64));
    if (lane == 0) red[wv] = mx;
    __syncthreads();
    mx = fmaxf(fmaxf(red[0], red[1]), fmaxf(red[2], red[3]));
    __syncthreads();

    float e0 = __expf(s0 - mx) * m0;
    float e1 = __expf(s1 - mx) * m1;
    float sm = e0 + e1;
#pragma unroll
    for (int w = 1; w <= 32; w <<= 1) sm += __shfl_xor(sm, w, 64);
    if (lane == 0) red[wv] = sm;
    __syncthreads();
    sm = (red[0] + red[1]) + (red[2] + red[3]);

    float inv = 1.0f / sm;
    scores_out[b * OBJ + t]       = e0 * inv;
    scores_out[b * OBJ + t + 256] = e1 * inv;
}

extern "C" void kernel_launch(void* const* d_in, const int* in_sizes, int n_in,
                              void* d_out, int out_size, void* d_ws, size_t ws_size,
                              hipStream_t stream)
{
    const float* h         = (const float*)d_in[0];
    const float* att_feats = (const float*)d_in[1];
    const int*   att_masks = (const int*)d_in[2];
    const float* W_h2att   = (const float*)d_in[3];
    const float* b_h2att   = (const float*)d_in[4];
    const float* w_alpha   = (const float*)d_in[5];
    // d_in[6] = b_alpha: constant shift, cancels exactly in softmax -> unused.

    float* att_h  = (float*)d_ws;        // BS*HID floats = 256 KB scratch
    float* scores = (float*)d_out;       // exactly BS*OBJ floats; K3 runs in-place

    k1_h2att  <<<dim3(1024), dim3(256), 0, stream>>>(h, W_h2att, att_h);
    k2_scores <<<dim3(2048), dim3(256), 0, stream>>>(att_feats, att_h, b_h2att,
                                                     w_alpha, scores);
    k3_softmax<<<dim3(BS),   dim3(256), 0, stream>>>(scores, att_masks);
}